// Round 1
// baseline (3129.667 us; speedup 1.0000x reference)
//
#include <hip/hip_runtime.h>

#define DIM 128

// ---------------- degree / norm ----------------
__global__ __launch_bounds__(256) void k_count(const int* __restrict__ dst,
                                               int* __restrict__ deg, int E) {
    int t = blockIdx.x * 256 + threadIdx.x;
    if (t < E) atomicAdd(&deg[dst[t]], 1);
}

__global__ __launch_bounds__(256) void k_dinv(const int* __restrict__ deg,
                                              float* __restrict__ dinv, int N) {
    int t = blockIdx.x * 256 + threadIdx.x;
    if (t < N) dinv[t] = rsqrtf((float)(deg[t] + 1));  // +1 = self-loop
}

// ---------------- dense GEMM: H[i][j] = (c[j]) + sum_k f(X[i][k]) * W[k][j] ----------------
// block = 512 threads: j = tid&127 (output column), r = tid>>7 (row within 4-row tile).
// W read from global (64KB, L2-resident, coalesced across j); X rows staged in LDS (2KB),
// read via wave-uniform broadcast.
template<bool RELU_IN, bool ADD_C>
__global__ __launch_bounds__(512) void k_gemm(const float* __restrict__ X,
                                              const float* __restrict__ W,
                                              const float* __restrict__ Cvec,
                                              float* __restrict__ H, int n) {
    __shared__ float sX[4][DIM];
    int j = threadIdx.x & (DIM - 1);
    int r = threadIdx.x >> 7;  // 0..3
    float cj = ADD_C ? Cvec[j] : 0.0f;
    for (int base = blockIdx.x * 4; base < n; base += gridDim.x * 4) {
        int i = base + r;
        float xv = (i < n) ? X[(size_t)i * DIM + j] : 0.0f;
        if (RELU_IN) xv = fmaxf(xv, 0.0f);
        __syncthreads();             // previous iteration's sX reads done
        sX[r][j] = xv;
        __syncthreads();
        float acc = cj;
        #pragma unroll 16
        for (int k = 0; k < DIM; ++k)
            acc = fmaf(sX[r][k], W[k * DIM + j], acc);
        if (i < n) H[(size_t)i * DIM + j] = acc;
    }
}

// ---------------- c[j] = sum_k relu(posts[root][k]) * W2[k][j] ----------------
__global__ __launch_bounds__(DIM) void k_cvec(const float* __restrict__ posts,
                                              const int* __restrict__ root,
                                              const float* __restrict__ W2,
                                              float* __restrict__ cvec) {
    int j = threadIdx.x;
    const float* xr = posts + (size_t)root[0] * DIM;
    float acc = 0.0f;
    #pragma unroll 8
    for (int k = 0; k < DIM; ++k)
        acc = fmaf(fmaxf(xr[k], 0.0f), W2[k * DIM + j], acc);
    cvec[j] = acc;
}

// ---------------- edge scatter: acc[dst] += h[src] * dinv[src]*dinv[dst] ----------------
// 32 threads per edge, float4 gather, 4 hardware f32 atomics per thread.
__global__ __launch_bounds__(256) void k_scatter(const int* __restrict__ src,
                                                 const int* __restrict__ dst,
                                                 const float* __restrict__ dinv,
                                                 const float* __restrict__ h,
                                                 float* __restrict__ acc, int E) {
    int t = blockIdx.x * 256 + threadIdx.x;
    int e = t >> 5;
    if (e >= E) return;
    int q = t & 31;
    int s = src[e], d = dst[e];
    float w = dinv[s] * dinv[d];
    float4 v = reinterpret_cast<const float4*>(h + (size_t)s * DIM)[q];
    float* ad = acc + (size_t)d * DIM + q * 4;
    unsafeAtomicAdd(ad + 0, v.x * w);
    unsafeAtomicAdd(ad + 1, v.y * w);
    unsafeAtomicAdd(ad + 2, v.z * w);
    unsafeAtomicAdd(ad + 3, v.w * w);
}

// ---------------- finalize layer1: acc = acc + h*dinv^2 + b1; write root row to out ----------------
__global__ __launch_bounds__(256) void k_final1(float* __restrict__ acc,
                                                const float* __restrict__ h,
                                                const float* __restrict__ dinv,
                                                const float* __restrict__ b1,
                                                const int* __restrict__ root,
                                                float* __restrict__ out, int N) {
    int t = blockIdx.x * 256 + threadIdx.x;
    if (t >= N * DIM) return;
    int i = t >> 7, j = t & (DIM - 1);
    float di = dinv[i];
    float val = acc[t] + h[t] * di * di + b1[j];
    acc[t] = val;
    if (i == root[0]) out[j] = val;   // conv1_root (no relu, matches reference)
}

// ---------------- finalize layer2 + column mean partials ----------------
__global__ __launch_bounds__(256) void k_final2(const float* __restrict__ acc,
                                                const float* __restrict__ h,
                                                const float* __restrict__ dinv,
                                                const float* __restrict__ b2,
                                                float* __restrict__ partial, int N) {
    int j = threadIdx.x & (DIM - 1);
    int r = threadIdx.x >> 7;  // 0..1
    float b = b2[j];
    float sum = 0.0f;
    for (int i = blockIdx.x * 2 + r; i < N; i += gridDim.x * 2) {
        size_t t = (size_t)i * DIM + j;
        float di = dinv[i];
        float v = acc[t] + h[t] * di * di + b;
        sum += fmaxf(v, 0.0f);
    }
    __shared__ float sp[2][DIM];
    sp[r][j] = sum;
    __syncthreads();
    if (r == 0) partial[(size_t)blockIdx.x * DIM + j] = sp[0][j] + sp[1][j];
}

__global__ __launch_bounds__(DIM) void k_reduce(const float* __restrict__ partial,
                                                float* __restrict__ out, int nb, int N) {
    int j = threadIdx.x;
    float s = 0.0f;
    for (int b = 0; b < nb; ++b) s += partial[(size_t)b * DIM + j];
    out[DIM + j] = s / (float)N;
}

extern "C" void kernel_launch(void* const* d_in, const int* in_sizes, int n_in,
                              void* d_out, int out_size, void* d_ws, size_t ws_size,
                              hipStream_t stream) {
    const float* posts = (const float*)d_in[0];
    const int*   eidx  = (const int*)d_in[1];
    const int*   root  = (const int*)d_in[2];
    const float* W1    = (const float*)d_in[3];
    const float* b1    = (const float*)d_in[4];
    const float* W2    = (const float*)d_in[5];
    const float* b2    = (const float*)d_in[6];
    float* out = (float*)d_out;

    int N = in_sizes[0] / DIM;
    int E = in_sizes[1] / 2;
    const int* src = eidx;
    const int* dst = eidx + E;

    char* ws = (char*)d_ws;
    size_t off = 0;
    auto alloc = [&](size_t bytes) {
        void* p = ws + off;
        off += (bytes + 511) & ~(size_t)511;
        return p;
    };
    int*   deg     = (int*)  alloc((size_t)N * 4);
    float* dinv    = (float*)alloc((size_t)N * 4);
    float* cvec    = (float*)alloc(DIM * 4);
    const int G2 = 512;
    float* partial = (float*)alloc((size_t)G2 * DIM * 4);
    float* h       = (float*)alloc((size_t)N * DIM * 4);   // h1, then h2
    float* acc     = (float*)alloc((size_t)N * DIM * 4);   // conv1 accum -> conv1_out, then conv2 accum

    hipMemsetAsync(deg, 0, (size_t)N * 4, stream);
    hipMemsetAsync(acc, 0, (size_t)N * DIM * 4, stream);

    k_count<<<(E + 255) / 256, 256, 0, stream>>>(dst, deg, E);
    k_dinv<<<(N + 255) / 256, 256, 0, stream>>>(deg, dinv, N);

    // layer 1
    k_gemm<false, false><<<512, 512, 0, stream>>>(posts, W1, nullptr, h, N);
    k_scatter<<<(E * 32 + 255) / 256, 256, 0, stream>>>(src, dst, dinv, h, acc, E);
    k_final1<<<(N * DIM + 255) / 256, 256, 0, stream>>>(acc, h, dinv, b1, root, out, N);

    // layer 2: h2 = cvec + relu(conv1_out) @ W2[128:], cvec = relu(post_root) @ W2[:128]
    k_cvec<<<1, DIM, 0, stream>>>(posts, root, W2, cvec);
    k_gemm<true, true><<<512, 512, 0, stream>>>(acc, W2 + DIM * DIM, cvec, h, N);

    hipMemsetAsync(acc, 0, (size_t)N * DIM * 4, stream);
    k_scatter<<<(E * 32 + 255) / 256, 256, 0, stream>>>(src, dst, dinv, h, acc, E);
    k_final2<<<G2, 256, 0, stream>>>(acc, h, dinv, b2, partial, N);
    k_reduce<<<1, DIM, 0, stream>>>(partial, out, G2, N);
}

// Round 2
// 961.439 us; speedup vs baseline: 3.2552x; 3.2552x over previous
//
#include <hip/hip_runtime.h>

#define DIM 128

// ---------------- degree count ----------------
__global__ __launch_bounds__(256) void k_count(const int* __restrict__ dst,
                                               int* __restrict__ deg, int E) {
    int t = blockIdx.x * 256 + threadIdx.x;
    if (t < E) atomicAdd(&deg[dst[t]], 1);
}

__global__ __launch_bounds__(256) void k_dinv(const int* __restrict__ deg,
                                              float* __restrict__ dinv, int N) {
    int t = blockIdx.x * 256 + threadIdx.x;
    if (t < N) dinv[t] = rsqrtf((float)(deg[t] + 1));  // +1 = self-loop
}

// ---------------- single-block exclusive scan -> rowptr, cursor ----------------
__global__ __launch_bounds__(1024) void k_scan(const int* __restrict__ deg,
                                               int* __restrict__ rowptr,
                                               int* __restrict__ cursor, int N) {
    int t = threadIdx.x;
    int chunk = (N + 1023) >> 10;
    int s0 = t * chunk, s1 = min(s0 + chunk, N);
    int sum = 0;
    for (int i = s0; i < s1; ++i) sum += deg[i];
    __shared__ int ps[1024];
    ps[t] = sum;
    __syncthreads();
    for (int off = 1; off < 1024; off <<= 1) {
        int v = (t >= off) ? ps[t - off] : 0;
        __syncthreads();
        ps[t] += v;
        __syncthreads();
    }
    int base = (t == 0) ? 0 : ps[t - 1];
    for (int i = s0; i < s1; ++i) { rowptr[i] = base; cursor[i] = base; base += deg[i]; }
    if (t == 0) rowptr[N] = ps[1023];
}

// ---------------- CSR fill: {src, weight} per edge, grouped by dst ----------------
__global__ __launch_bounds__(256) void k_fill(const int* __restrict__ src,
                                              const int* __restrict__ dst,
                                              const float* __restrict__ dinv,
                                              int* __restrict__ cursor,
                                              int2* __restrict__ csr, int E) {
    int e = blockIdx.x * 256 + threadIdx.x;
    if (e >= E) return;
    int s = src[e], d = dst[e];
    int p = atomicAdd(&cursor[d], 1);
    float w = dinv[s] * dinv[d];
    csr[p] = make_int2(s, __float_as_int(w));
}

// ---------------- dense GEMM: H = (cvec +) f(X) @ W ----------------
// block 256: jq = tid&31 -> cols jq*4.., rr = tid>>5 -> rows rr*4.. of a 32-row tile.
// W staged in LDS in two 64-row K-chunks (32KB), X tile 16KB. 4x4 register blocking.
template<bool RELU_IN, bool ADD_C>
__global__ __launch_bounds__(256) void k_gemm(const float* __restrict__ X,
                                              const float* __restrict__ W,
                                              const float* __restrict__ Cvec,
                                              float* __restrict__ H, int n) {
    __shared__ float sW[64 * DIM];   // 32 KB, one K-chunk of W [k2][j]
    __shared__ float sX[32][DIM];    // 16 KB
    const int jq = threadIdx.x & 31;
    const int rr = threadIdx.x >> 5;   // 0..7
    float4 cj = ADD_C ? ((const float4*)Cvec)[jq] : make_float4(0.f, 0.f, 0.f, 0.f);
    for (int base = blockIdx.x * 32; base < n; base += gridDim.x * 32) {
        __syncthreads();   // everyone done with previous tile's sX/sW
        for (int u = threadIdx.x; u < 32 * 32; u += 256) {
            int row = u >> 5, c4 = u & 31;
            int gi = base + row;
            float4 v = make_float4(0.f, 0.f, 0.f, 0.f);
            if (gi < n) v = ((const float4*)(X + (size_t)gi * DIM))[c4];
            if (RELU_IN) {
                v.x = fmaxf(v.x, 0.f); v.y = fmaxf(v.y, 0.f);
                v.z = fmaxf(v.z, 0.f); v.w = fmaxf(v.w, 0.f);
            }
            ((float4*)sX[row])[c4] = v;
        }
        float4 a0 = cj, a1 = cj, a2 = cj, a3 = cj;
        for (int kk = 0; kk < DIM; kk += 64) {
            __syncthreads();   // sX staged (first iter) / prev chunk compute done
            for (int u = threadIdx.x; u < 64 * 32; u += 256)
                ((float4*)sW)[u] = ((const float4*)(W + (size_t)kk * DIM))[u];
            __syncthreads();
            #pragma unroll 8
            for (int k2 = 0; k2 < 64; ++k2) {
                int k = kk + k2;
                float4 w4 = ((const float4*)sW)[k2 * 32 + jq];
                float x0 = sX[rr * 4 + 0][k], x1 = sX[rr * 4 + 1][k];
                float x2 = sX[rr * 4 + 2][k], x3 = sX[rr * 4 + 3][k];
                a0.x = fmaf(x0, w4.x, a0.x); a0.y = fmaf(x0, w4.y, a0.y);
                a0.z = fmaf(x0, w4.z, a0.z); a0.w = fmaf(x0, w4.w, a0.w);
                a1.x = fmaf(x1, w4.x, a1.x); a1.y = fmaf(x1, w4.y, a1.y);
                a1.z = fmaf(x1, w4.z, a1.z); a1.w = fmaf(x1, w4.w, a1.w);
                a2.x = fmaf(x2, w4.x, a2.x); a2.y = fmaf(x2, w4.y, a2.y);
                a2.z = fmaf(x2, w4.z, a2.z); a2.w = fmaf(x2, w4.w, a2.w);
                a3.x = fmaf(x3, w4.x, a3.x); a3.y = fmaf(x3, w4.y, a3.y);
                a3.z = fmaf(x3, w4.z, a3.z); a3.w = fmaf(x3, w4.w, a3.w);
            }
        }
        int i0 = base + rr * 4;
        if (i0 + 0 < n) ((float4*)(H + (size_t)(i0 + 0) * DIM))[jq] = a0;
        if (i0 + 1 < n) ((float4*)(H + (size_t)(i0 + 1) * DIM))[jq] = a1;
        if (i0 + 2 < n) ((float4*)(H + (size_t)(i0 + 2) * DIM))[jq] = a2;
        if (i0 + 3 < n) ((float4*)(H + (size_t)(i0 + 3) * DIM))[jq] = a3;
    }
}

// ---------------- c[j] = sum_k relu(posts[root][k]) * W2[k][j] ----------------
__global__ __launch_bounds__(DIM) void k_cvec(const float* __restrict__ posts,
                                              const int* __restrict__ root,
                                              const float* __restrict__ W2,
                                              float* __restrict__ cvec) {
    int j = threadIdx.x;
    const float* xr = posts + (size_t)root[0] * DIM;
    float acc = 0.0f;
    #pragma unroll 8
    for (int k = 0; k < DIM; ++k)
        acc = fmaf(fmaxf(xr[k], 0.0f), W2[k * DIM + j], acc);
    cvec[j] = acc;
}

// ---------------- gather layer 1: conv1 = A_norm @ h + self + b1 ----------------
// 32 lanes per node, float4 per lane, 2-edge unroll.
__global__ __launch_bounds__(256) void k_gather1(const int2* __restrict__ csr,
                                                 const int* __restrict__ rowptr,
                                                 const float* __restrict__ dinv,
                                                 const float* __restrict__ h,
                                                 const float* __restrict__ b1,
                                                 const int* __restrict__ root,
                                                 float* __restrict__ conv1,
                                                 float* __restrict__ out, int N) {
    int t = blockIdx.x * 256 + threadIdx.x;
    int d = t >> 5, q = t & 31;
    if (d >= N) return;
    int beg = rowptr[d], end = rowptr[d + 1];
    float ax = 0.f, ay = 0.f, az = 0.f, aw = 0.f;
    int e = beg;
    for (; e + 2 <= end; e += 2) {
        int2 e0 = csr[e], e1 = csr[e + 1];
        float w0 = __int_as_float(e0.y), w1 = __int_as_float(e1.y);
        float4 v0 = ((const float4*)(h + (size_t)e0.x * DIM))[q];
        float4 v1 = ((const float4*)(h + (size_t)e1.x * DIM))[q];
        ax = fmaf(v0.x, w0, ax); ay = fmaf(v0.y, w0, ay);
        az = fmaf(v0.z, w0, az); aw = fmaf(v0.w, w0, aw);
        ax = fmaf(v1.x, w1, ax); ay = fmaf(v1.y, w1, ay);
        az = fmaf(v1.z, w1, az); aw = fmaf(v1.w, w1, aw);
    }
    if (e < end) {
        int2 e0 = csr[e];
        float w0 = __int_as_float(e0.y);
        float4 v0 = ((const float4*)(h + (size_t)e0.x * DIM))[q];
        ax = fmaf(v0.x, w0, ax); ay = fmaf(v0.y, w0, ay);
        az = fmaf(v0.z, w0, az); aw = fmaf(v0.w, w0, aw);
    }
    float di = dinv[d], sl = di * di;
    float4 hv = ((const float4*)(h + (size_t)d * DIM))[q];
    float4 bv = ((const float4*)b1)[q];
    float4 r;
    r.x = fmaf(hv.x, sl, ax) + bv.x;
    r.y = fmaf(hv.y, sl, ay) + bv.y;
    r.z = fmaf(hv.z, sl, az) + bv.z;
    r.w = fmaf(hv.w, sl, aw) + bv.w;
    ((float4*)(conv1 + (size_t)d * DIM))[q] = r;
    if (d == root[0]) ((float4*)out)[q] = r;   // conv1_root (no relu)
}

// ---------------- gather layer 2 + relu + fused column-mean ----------------
__global__ __launch_bounds__(256) void k_gather2(const int2* __restrict__ csr,
                                                 const int* __restrict__ rowptr,
                                                 const float* __restrict__ dinv,
                                                 const float* __restrict__ h,
                                                 const float* __restrict__ b2,
                                                 float* __restrict__ meanacc, int N) {
    int t = blockIdx.x * 256 + threadIdx.x;
    int d = t >> 5, q = t & 31;
    bool active = d < N;
    int dd = active ? d : 0;
    int beg = rowptr[dd], end = active ? rowptr[dd + 1] : rowptr[dd];
    float ax = 0.f, ay = 0.f, az = 0.f, aw = 0.f;
    int e = beg;
    for (; e + 2 <= end; e += 2) {
        int2 e0 = csr[e], e1 = csr[e + 1];
        float w0 = __int_as_float(e0.y), w1 = __int_as_float(e1.y);
        float4 v0 = ((const float4*)(h + (size_t)e0.x * DIM))[q];
        float4 v1 = ((const float4*)(h + (size_t)e1.x * DIM))[q];
        ax = fmaf(v0.x, w0, ax); ay = fmaf(v0.y, w0, ay);
        az = fmaf(v0.z, w0, az); aw = fmaf(v0.w, w0, aw);
        ax = fmaf(v1.x, w1, ax); ay = fmaf(v1.y, w1, ay);
        az = fmaf(v1.z, w1, az); aw = fmaf(v1.w, w1, aw);
    }
    if (e < end) {
        int2 e0 = csr[e];
        float w0 = __int_as_float(e0.y);
        float4 v0 = ((const float4*)(h + (size_t)e0.x * DIM))[q];
        ax = fmaf(v0.x, w0, ax); ay = fmaf(v0.y, w0, ay);
        az = fmaf(v0.z, w0, az); aw = fmaf(v0.w, w0, aw);
    }
    float4 r = make_float4(0.f, 0.f, 0.f, 0.f);
    if (active) {
        float di = dinv[dd], sl = di * di;
        float4 hv = ((const float4*)(h + (size_t)dd * DIM))[q];
        float4 bv = ((const float4*)b2)[q];
        r.x = fmaxf(fmaf(hv.x, sl, ax) + bv.x, 0.f);
        r.y = fmaxf(fmaf(hv.y, sl, ay) + bv.y, 0.f);
        r.z = fmaxf(fmaf(hv.z, sl, az) + bv.z, 0.f);
        r.w = fmaxf(fmaf(hv.w, sl, aw) + bv.w, 0.f);
    }
    __shared__ float4 sp[256];
    sp[threadIdx.x] = r;
    __syncthreads();
    if (threadIdx.x < 32) {
        float4 s = sp[threadIdx.x];
        #pragma unroll
        for (int g = 1; g < 8; ++g) {
            float4 o = sp[g * 32 + threadIdx.x];
            s.x += o.x; s.y += o.y; s.z += o.z; s.w += o.w;
        }
        unsafeAtomicAdd(&meanacc[q * 4 + 0], s.x);
        unsafeAtomicAdd(&meanacc[q * 4 + 1], s.y);
        unsafeAtomicAdd(&meanacc[q * 4 + 2], s.z);
        unsafeAtomicAdd(&meanacc[q * 4 + 3], s.w);
    }
}

__global__ __launch_bounds__(DIM) void k_reduce(const float* __restrict__ meanacc,
                                                float* __restrict__ out, int N) {
    int j = threadIdx.x;
    out[DIM + j] = meanacc[j] / (float)N;
}

extern "C" void kernel_launch(void* const* d_in, const int* in_sizes, int n_in,
                              void* d_out, int out_size, void* d_ws, size_t ws_size,
                              hipStream_t stream) {
    const float* posts = (const float*)d_in[0];
    const int*   eidx  = (const int*)d_in[1];
    const int*   root  = (const int*)d_in[2];
    const float* W1    = (const float*)d_in[3];
    const float* b1    = (const float*)d_in[4];
    const float* W2    = (const float*)d_in[5];
    const float* b2    = (const float*)d_in[6];
    float* out = (float*)d_out;

    int N = in_sizes[0] / DIM;
    int E = in_sizes[1] / 2;
    const int* src = eidx;
    const int* dst = eidx + E;

    char* ws = (char*)d_ws;
    size_t off = 0;
    auto alloc = [&](size_t bytes) {
        void* p = ws + off;
        off += (bytes + 511) & ~(size_t)511;
        return p;
    };
    int*   deg     = (int*)  alloc((size_t)N * 4);
    int*   rowptr  = (int*)  alloc((size_t)(N + 1) * 4);
    int*   cursor  = (int*)  alloc((size_t)N * 4);
    float* dinv    = (float*)alloc((size_t)N * 4);
    float* cvec    = (float*)alloc(DIM * 4);
    float* meanacc = (float*)alloc(DIM * 4);
    int2*  csr     = (int2*) alloc((size_t)E * 8);
    float* h       = (float*)alloc((size_t)N * DIM * 4);   // h1, then h2
    float* conv1   = (float*)alloc((size_t)N * DIM * 4);   // conv1_out

    hipMemsetAsync(deg, 0, (size_t)N * 4, stream);
    hipMemsetAsync(meanacc, 0, DIM * 4, stream);

    // CSR build (once, shared by both layers)
    k_count<<<(E + 255) / 256, 256, 0, stream>>>(dst, deg, E);
    k_scan<<<1, 1024, 0, stream>>>(deg, rowptr, cursor, N);
    k_dinv<<<(N + 255) / 256, 256, 0, stream>>>(deg, dinv, N);
    k_fill<<<(E + 255) / 256, 256, 0, stream>>>(src, dst, dinv, cursor, csr, E);

    // layer 1
    k_gemm<false, false><<<512, 256, 0, stream>>>(posts, W1, nullptr, h, N);
    k_gather1<<<(N * 32 + 255) / 256, 256, 0, stream>>>(csr, rowptr, dinv, h, b1, root,
                                                        conv1, out, N);

    // layer 2: h2 = cvec + relu(conv1) @ W2[128:], cvec = relu(post_root) @ W2[:128]
    k_cvec<<<1, DIM, 0, stream>>>(posts, root, W2, cvec);
    k_gemm<true, true><<<512, 256, 0, stream>>>(conv1, W2 + DIM * DIM, cvec, h, N);
    k_gather2<<<(N * 32 + 255) / 256, 256, 0, stream>>>(csr, rowptr, dinv, h, b2,
                                                        meanacc, N);
    k_reduce<<<1, DIM, 0, stream>>>(meanacc, out, N);
}

// Round 3
// 584.045 us; speedup vs baseline: 5.3586x; 1.6462x over previous
//
#include <hip/hip_runtime.h>

#define DIM 128

// ---------------- degree count ----------------
__global__ __launch_bounds__(256) void k_count(const int* __restrict__ dst,
                                               int* __restrict__ deg, int E) {
    int t = blockIdx.x * 256 + threadIdx.x;
    if (t < E) atomicAdd(&deg[dst[t]], 1);
}

__global__ __launch_bounds__(256) void k_dinv(const int* __restrict__ deg,
                                              float* __restrict__ dinv, int N) {
    int t = blockIdx.x * 256 + threadIdx.x;
    if (t < N) dinv[t] = rsqrtf((float)(deg[t] + 1));  // +1 = self-loop
}

// ---------------- single-block exclusive scan -> rowptr, cursor ----------------
__global__ __launch_bounds__(1024) void k_scan(const int* __restrict__ deg,
                                               int* __restrict__ rowptr,
                                               int* __restrict__ cursor, int N) {
    int t = threadIdx.x;
    int chunk = (N + 1023) >> 10;
    int s0 = t * chunk, s1 = min(s0 + chunk, N);
    int sum = 0;
    for (int i = s0; i < s1; ++i) sum += deg[i];
    __shared__ int ps[1024];
    ps[t] = sum;
    __syncthreads();
    for (int off = 1; off < 1024; off <<= 1) {
        int v = (t >= off) ? ps[t - off] : 0;
        __syncthreads();
        ps[t] += v;
        __syncthreads();
    }
    int base = (t == 0) ? 0 : ps[t - 1];
    for (int i = s0; i < s1; ++i) { rowptr[i] = base; cursor[i] = base; base += deg[i]; }
    if (t == 0) rowptr[N] = ps[1023];
}

// ---------------- CSR fill: {src, weight} per edge, grouped by dst ----------------
__global__ __launch_bounds__(256) void k_fill(const int* __restrict__ src,
                                              const int* __restrict__ dst,
                                              const float* __restrict__ dinv,
                                              int* __restrict__ cursor,
                                              int2* __restrict__ csr, int E) {
    int e = blockIdx.x * 256 + threadIdx.x;
    if (e >= E) return;
    int s = src[e], d = dst[e];
    int p = atomicAdd(&cursor[d], 1);
    float w = dinv[s] * dinv[d];
    csr[p] = make_int2(s, __float_as_int(w));
}

// ---------------- dense GEMM: H = (cvec +) f(X) @ W ----------------
template<bool RELU_IN, bool ADD_C>
__global__ __launch_bounds__(256) void k_gemm(const float* __restrict__ X,
                                              const float* __restrict__ W,
                                              const float* __restrict__ Cvec,
                                              float* __restrict__ H, int n) {
    __shared__ float sW[64 * DIM];   // 32 KB, one K-chunk of W [k2][j]
    __shared__ float sX[32][DIM];    // 16 KB
    const int jq = threadIdx.x & 31;
    const int rr = threadIdx.x >> 5;   // 0..7
    float4 cj = ADD_C ? ((const float4*)Cvec)[jq] : make_float4(0.f, 0.f, 0.f, 0.f);
    for (int base = blockIdx.x * 32; base < n; base += gridDim.x * 32) {
        __syncthreads();
        for (int u = threadIdx.x; u < 32 * 32; u += 256) {
            int row = u >> 5, c4 = u & 31;
            int gi = base + row;
            float4 v = make_float4(0.f, 0.f, 0.f, 0.f);
            if (gi < n) v = ((const float4*)(X + (size_t)gi * DIM))[c4];
            if (RELU_IN) {
                v.x = fmaxf(v.x, 0.f); v.y = fmaxf(v.y, 0.f);
                v.z = fmaxf(v.z, 0.f); v.w = fmaxf(v.w, 0.f);
            }
            ((float4*)sX[row])[c4] = v;
        }
        float4 a0 = cj, a1 = cj, a2 = cj, a3 = cj;
        for (int kk = 0; kk < DIM; kk += 64) {
            __syncthreads();
            for (int u = threadIdx.x; u < 64 * 32; u += 256)
                ((float4*)sW)[u] = ((const float4*)(W + (size_t)kk * DIM))[u];
            __syncthreads();
            #pragma unroll 8
            for (int k2 = 0; k2 < 64; ++k2) {
                int k = kk + k2;
                float4 w4 = ((const float4*)sW)[k2 * 32 + jq];
                float x0 = sX[rr * 4 + 0][k], x1 = sX[rr * 4 + 1][k];
                float x2 = sX[rr * 4 + 2][k], x3 = sX[rr * 4 + 3][k];
                a0.x = fmaf(x0, w4.x, a0.x); a0.y = fmaf(x0, w4.y, a0.y);
                a0.z = fmaf(x0, w4.z, a0.z); a0.w = fmaf(x0, w4.w, a0.w);
                a1.x = fmaf(x1, w4.x, a1.x); a1.y = fmaf(x1, w4.y, a1.y);
                a1.z = fmaf(x1, w4.z, a1.z); a1.w = fmaf(x1, w4.w, a1.w);
                a2.x = fmaf(x2, w4.x, a2.x); a2.y = fmaf(x2, w4.y, a2.y);
                a2.z = fmaf(x2, w4.z, a2.z); a2.w = fmaf(x2, w4.w, a2.w);
                a3.x = fmaf(x3, w4.x, a3.x); a3.y = fmaf(x3, w4.y, a3.y);
                a3.z = fmaf(x3, w4.z, a3.z); a3.w = fmaf(x3, w4.w, a3.w);
            }
        }
        int i0 = base + rr * 4;
        if (i0 + 0 < n) ((float4*)(H + (size_t)(i0 + 0) * DIM))[jq] = a0;
        if (i0 + 1 < n) ((float4*)(H + (size_t)(i0 + 1) * DIM))[jq] = a1;
        if (i0 + 2 < n) ((float4*)(H + (size_t)(i0 + 2) * DIM))[jq] = a2;
        if (i0 + 3 < n) ((float4*)(H + (size_t)(i0 + 3) * DIM))[jq] = a3;
    }
}

// ---------------- c[j] = sum_k relu(posts[root][k]) * W2[k][j] ----------------
__global__ __launch_bounds__(DIM) void k_cvec(const float* __restrict__ posts,
                                              const int* __restrict__ root,
                                              const float* __restrict__ W2,
                                              float* __restrict__ cvec) {
    int j = threadIdx.x;
    const float* xr = posts + (size_t)root[0] * DIM;
    float acc = 0.0f;
    #pragma unroll 8
    for (int k = 0; k < DIM; ++k)
        acc = fmaf(fmaxf(xr[k], 0.0f), W2[k * DIM + j], acc);
    cvec[j] = acc;
}

// 4-edge-unrolled accumulate of h rows into (ax,ay,az,aw) for lane-quad q.
__device__ __forceinline__ void edge_accum(const int2* __restrict__ csr,
                                           int beg, int end, int q,
                                           const float* __restrict__ h,
                                           float& ax, float& ay, float& az, float& aw) {
    int e = beg;
    for (; e + 4 <= end; e += 4) {
        int2 e0 = csr[e], e1 = csr[e + 1], e2 = csr[e + 2], e3 = csr[e + 3];
        float w0 = __int_as_float(e0.y), w1 = __int_as_float(e1.y);
        float w2 = __int_as_float(e2.y), w3 = __int_as_float(e3.y);
        float4 v0 = ((const float4*)(h + (size_t)e0.x * DIM))[q];
        float4 v1 = ((const float4*)(h + (size_t)e1.x * DIM))[q];
        float4 v2 = ((const float4*)(h + (size_t)e2.x * DIM))[q];
        float4 v3 = ((const float4*)(h + (size_t)e3.x * DIM))[q];
        ax = fmaf(v0.x, w0, ax); ay = fmaf(v0.y, w0, ay);
        az = fmaf(v0.z, w0, az); aw = fmaf(v0.w, w0, aw);
        ax = fmaf(v1.x, w1, ax); ay = fmaf(v1.y, w1, ay);
        az = fmaf(v1.z, w1, az); aw = fmaf(v1.w, w1, aw);
        ax = fmaf(v2.x, w2, ax); ay = fmaf(v2.y, w2, ay);
        az = fmaf(v2.z, w2, az); aw = fmaf(v2.w, w2, aw);
        ax = fmaf(v3.x, w3, ax); ay = fmaf(v3.y, w3, ay);
        az = fmaf(v3.z, w3, az); aw = fmaf(v3.w, w3, aw);
    }
    for (; e < end; ++e) {
        int2 e0 = csr[e];
        float w0 = __int_as_float(e0.y);
        float4 v0 = ((const float4*)(h + (size_t)e0.x * DIM))[q];
        ax = fmaf(v0.x, w0, ax); ay = fmaf(v0.y, w0, ay);
        az = fmaf(v0.z, w0, az); aw = fmaf(v0.w, w0, aw);
    }
}

// ---------------- gather layer 1: conv1 = A_norm @ h + self + b1 ----------------
__global__ __launch_bounds__(256) void k_gather1(const int2* __restrict__ csr,
                                                 const int* __restrict__ rowptr,
                                                 const float* __restrict__ dinv,
                                                 const float* __restrict__ h,
                                                 const float* __restrict__ b1,
                                                 const int* __restrict__ root,
                                                 float* __restrict__ conv1,
                                                 float* __restrict__ out, int N) {
    int t = blockIdx.x * 256 + threadIdx.x;
    int d = t >> 5, q = t & 31;
    if (d >= N) return;
    int beg = rowptr[d], end = rowptr[d + 1];
    float ax = 0.f, ay = 0.f, az = 0.f, aw = 0.f;
    edge_accum(csr, beg, end, q, h, ax, ay, az, aw);
    float di = dinv[d], sl = di * di;
    float4 hv = ((const float4*)(h + (size_t)d * DIM))[q];
    float4 bv = ((const float4*)b1)[q];
    float4 r;
    r.x = fmaf(hv.x, sl, ax) + bv.x;
    r.y = fmaf(hv.y, sl, ay) + bv.y;
    r.z = fmaf(hv.z, sl, az) + bv.z;
    r.w = fmaf(hv.w, sl, aw) + bv.w;
    ((float4*)(conv1 + (size_t)d * DIM))[q] = r;
    if (d == root[0]) ((float4*)out)[q] = r;   // conv1_root (no relu)
}

// ---------------- gather layer 2 + relu + fused column-mean (grid-stride) ----------------
__global__ __launch_bounds__(256) void k_gather2(const int2* __restrict__ csr,
                                                 const int* __restrict__ rowptr,
                                                 const float* __restrict__ dinv,
                                                 const float* __restrict__ h,
                                                 const float* __restrict__ b2,
                                                 float* __restrict__ meanacc, int N) {
    int q = threadIdx.x & 31;
    int g = threadIdx.x >> 5;   // 0..7: node-group within block
    float4 bv = ((const float4*)b2)[q];
    float sx = 0.f, sy = 0.f, sz = 0.f, sw = 0.f;  // running column sum (this thread)
    for (int d = blockIdx.x * 8 + g; d < N; d += gridDim.x * 8) {
        int beg = rowptr[d], end = rowptr[d + 1];
        float ax = 0.f, ay = 0.f, az = 0.f, aw = 0.f;
        edge_accum(csr, beg, end, q, h, ax, ay, az, aw);
        float di = dinv[d], sl = di * di;
        float4 hv = ((const float4*)(h + (size_t)d * DIM))[q];
        sx += fmaxf(fmaf(hv.x, sl, ax) + bv.x, 0.f);
        sy += fmaxf(fmaf(hv.y, sl, ay) + bv.y, 0.f);
        sz += fmaxf(fmaf(hv.z, sl, az) + bv.z, 0.f);
        sw += fmaxf(fmaf(hv.w, sl, aw) + bv.w, 0.f);
    }
    __shared__ float4 sp[256];
    sp[threadIdx.x] = make_float4(sx, sy, sz, sw);
    __syncthreads();
    if (threadIdx.x < 32) {
        float4 s = sp[threadIdx.x];
        #pragma unroll
        for (int gg = 1; gg < 8; ++gg) {
            float4 o = sp[gg * 32 + threadIdx.x];
            s.x += o.x; s.y += o.y; s.z += o.z; s.w += o.w;
        }
        unsafeAtomicAdd(&meanacc[q * 4 + 0], s.x);
        unsafeAtomicAdd(&meanacc[q * 4 + 1], s.y);
        unsafeAtomicAdd(&meanacc[q * 4 + 2], s.z);
        unsafeAtomicAdd(&meanacc[q * 4 + 3], s.w);
    }
}

__global__ __launch_bounds__(DIM) void k_reduce(const float* __restrict__ meanacc,
                                                float* __restrict__ out, int N) {
    int j = threadIdx.x;
    out[DIM + j] = meanacc[j] / (float)N;
}

extern "C" void kernel_launch(void* const* d_in, const int* in_sizes, int n_in,
                              void* d_out, int out_size, void* d_ws, size_t ws_size,
                              hipStream_t stream) {
    const float* posts = (const float*)d_in[0];
    const int*   eidx  = (const int*)d_in[1];
    const int*   root  = (const int*)d_in[2];
    const float* W1    = (const float*)d_in[3];
    const float* b1    = (const float*)d_in[4];
    const float* W2    = (const float*)d_in[5];
    const float* b2    = (const float*)d_in[6];
    float* out = (float*)d_out;

    int N = in_sizes[0] / DIM;
    int E = in_sizes[1] / 2;
    const int* src = eidx;
    const int* dst = eidx + E;

    char* ws = (char*)d_ws;
    size_t off = 0;
    auto alloc = [&](size_t bytes) {
        void* p = ws + off;
        off += (bytes + 511) & ~(size_t)511;
        return p;
    };
    int*   deg     = (int*)  alloc((size_t)N * 4);
    int*   rowptr  = (int*)  alloc((size_t)(N + 1) * 4);
    int*   cursor  = (int*)  alloc((size_t)N * 4);
    float* dinv    = (float*)alloc((size_t)N * 4);
    float* cvec    = (float*)alloc(DIM * 4);
    float* meanacc = (float*)alloc(DIM * 4);
    int2*  csr     = (int2*) alloc((size_t)E * 8);
    float* h       = (float*)alloc((size_t)N * DIM * 4);   // h1, then h2
    float* conv1   = (float*)alloc((size_t)N * DIM * 4);   // conv1_out

    hipMemsetAsync(deg, 0, (size_t)N * 4, stream);
    hipMemsetAsync(meanacc, 0, DIM * 4, stream);

    // CSR build (once, shared by both layers)
    k_count<<<(E + 255) / 256, 256, 0, stream>>>(dst, deg, E);
    k_scan<<<1, 1024, 0, stream>>>(deg, rowptr, cursor, N);
    k_dinv<<<(N + 255) / 256, 256, 0, stream>>>(deg, dinv, N);
    k_fill<<<(E + 255) / 256, 256, 0, stream>>>(src, dst, dinv, cursor, csr, E);

    // layer 1
    k_gemm<false, false><<<512, 256, 0, stream>>>(posts, W1, nullptr, h, N);
    k_gather1<<<(N * 32 + 255) / 256, 256, 0, stream>>>(csr, rowptr, dinv, h, b1, root,
                                                        conv1, out, N);

    // layer 2: h2 = cvec + relu(conv1) @ W2[128:], cvec = relu(post_root) @ W2[:128]
    k_cvec<<<1, DIM, 0, stream>>>(posts, root, W2, cvec);
    k_gemm<true, true><<<512, 256, 0, stream>>>(conv1, W2 + DIM * DIM, cvec, h, N);
    k_gather2<<<2048, 256, 0, stream>>>(csr, rowptr, dinv, h, b2, meanacc, N);
    k_reduce<<<1, DIM, 0, stream>>>(meanacc, out, N);
}